// Round 3
// baseline (494.870 us; speedup 1.0000x reference)
//
#include <hip/hip_runtime.h>

#define N_NODES 50000
#define N_EDGES 640000
// channels: 128 -> 128 -> 128 -> 64, residual 128 -> 64

// ---------------- graph build ----------------

__global__ void k_init(int* __restrict__ cnt, int* __restrict__ cursor) {
    int i = blockIdx.x * blockDim.x + threadIdx.x;
    if (i < N_NODES) { cnt[i] = 0; cursor[i] = 0; }
}

__global__ void k_count(const int* __restrict__ ei, int* __restrict__ cnt) {
    int e = blockIdx.x * blockDim.x + threadIdx.x;
    if (e < N_EDGES) atomicAdd(&cnt[ei[N_EDGES + e]], 1);
}

// scan over cnt -> offsets (exclusive); also emits dinv = rsqrt(cnt+1)
__global__ void k_scan1(const int* __restrict__ cnt, int* __restrict__ offsets,
                        int* __restrict__ partials, float* __restrict__ dinv) {
    __shared__ int s[256];
    int t = threadIdx.x;
    int i = blockIdx.x * 256 + t;
    int v = (i < N_NODES) ? cnt[i] : 0;
    if (i < N_NODES) dinv[i] = rsqrtf((float)(v + 1));  // +1 self-loop, always > 0
    s[t] = v;
    __syncthreads();
    #pragma unroll
    for (int d = 1; d < 256; d <<= 1) {
        int add = (t >= d) ? s[t - d] : 0;
        __syncthreads();
        s[t] += add;
        __syncthreads();
    }
    if (i < N_NODES) offsets[i + 1] = s[t];   // inclusive within block
    if (t == 255) partials[blockIdx.x] = s[255];
    if (i == 0) offsets[0] = 0;
}

__global__ void k_scan2(int* __restrict__ partials, int nb) {
    __shared__ int s[256];
    int t = threadIdx.x;
    int v = (t < nb) ? partials[t] : 0;
    s[t] = v;
    __syncthreads();
    #pragma unroll
    for (int d = 1; d < 256; d <<= 1) {
        int add = (t >= d) ? s[t - d] : 0;
        __syncthreads();
        s[t] += add;
        __syncthreads();
    }
    if (t < nb) partials[t] = s[t] - v;        // exclusive block bases
}

__global__ void k_scan3(int* __restrict__ offsets, const int* __restrict__ partials) {
    int i = blockIdx.x * 256 + threadIdx.x;
    if (i < N_NODES) offsets[i + 1] += partials[blockIdx.x];
}

__global__ void k_fill(const int* __restrict__ ei, const float* __restrict__ dinv,
                       const int* __restrict__ offsets, int* __restrict__ cursor,
                       int* __restrict__ csr_src, float* __restrict__ csr_w) {
    int e = blockIdx.x * blockDim.x + threadIdx.x;
    if (e < N_EDGES) {
        int r = ei[e];
        int c = ei[N_EDGES + e];
        float w = dinv[r] * dinv[c];
        int p = atomicAdd(&cursor[c], 1);
        int idx = offsets[c] + p;
        csr_src[idx] = r;
        csr_w[idx] = w;
    }
}

// ---------------- K1: O[N,128] = x[N,128] @ W[128,128] (no bias) ----------------
// A from global (coalesced, each row read once per block), W from global (L2 broadcast).
// 512 threads, BM=128 rows/block, 8 rows x 4 cols per thread. No LDS.

__global__ __launch_bounds__(512, 4)
void k_gemm_x(const float* __restrict__ A, const float* __restrict__ W,
              float* __restrict__ O) {
    int t = threadIdx.x;
    int tx = t & 31;          // float4 col group (128 cols)
    int ty = t >> 5;          // 16 row groups x 8 rows
    int base = blockIdx.x * 128;

    float acc[8][4];
    #pragma unroll
    for (int r = 0; r < 8; ++r) { acc[r][0]=0.f; acc[r][1]=0.f; acc[r][2]=0.f; acc[r][3]=0.f; }

    int rows[8];
    #pragma unroll
    for (int r = 0; r < 8; ++r) {
        int gr = base + ty * 8 + r;
        rows[r] = (gr < N_NODES) ? gr : (N_NODES - 1);  // clamp for safe load
    }

    #pragma unroll 2
    for (int k = 0; k < 128; k += 4) {
        float4 w0 = ((const float4*)(W + (size_t)(k + 0) * 128))[tx];
        float4 w1 = ((const float4*)(W + (size_t)(k + 1) * 128))[tx];
        float4 w2 = ((const float4*)(W + (size_t)(k + 2) * 128))[tx];
        float4 w3 = ((const float4*)(W + (size_t)(k + 3) * 128))[tx];
        #pragma unroll
        for (int r = 0; r < 8; ++r) {
            float4 xv = *(const float4*)(A + (size_t)rows[r] * 128 + k);
            acc[r][0] = fmaf(xv.x, w0.x, fmaf(xv.y, w1.x, fmaf(xv.z, w2.x, fmaf(xv.w, w3.x, acc[r][0]))));
            acc[r][1] = fmaf(xv.x, w0.y, fmaf(xv.y, w1.y, fmaf(xv.z, w2.y, fmaf(xv.w, w3.y, acc[r][1]))));
            acc[r][2] = fmaf(xv.x, w0.z, fmaf(xv.y, w1.z, fmaf(xv.z, w2.z, fmaf(xv.w, w3.z, acc[r][2]))));
            acc[r][3] = fmaf(xv.x, w0.w, fmaf(xv.y, w1.w, fmaf(xv.z, w2.w, fmaf(xv.w, w3.w, acc[r][3]))));
        }
    }

    #pragma unroll
    for (int r = 0; r < 8; ++r) {
        int gr = base + ty * 8 + r;
        if (gr < N_NODES)
            ((float4*)(O + (size_t)gr * 128))[tx] =
                make_float4(acc[r][0], acc[r][1], acc[r][2], acc[r][3]);
    }
}

// ---------------- fused: h = relu(agg128(T) + ba); O = h @ W[128,OUTC] ----------------
// 512 threads, BM=128 dst nodes/block. Phase A: 8 waves x 16 nodes, float2/lane gather.
// h-tile in LDS (64KB) -> 2 blocks/CU. W read from global (L2 broadcast).

template <int OUTC>
__global__ __launch_bounds__(512, 4)
void k_agg_gemm(const float* __restrict__ T, const int* __restrict__ offs,
                const int* __restrict__ csr_src, const float* __restrict__ csr_w,
                const float* __restrict__ dinv, const float* __restrict__ ba,
                const float* __restrict__ W, float* __restrict__ O) {
    __shared__ float sh[128 * 128];
    int t = threadIdx.x;
    int wave = t >> 6, lane = t & 63;
    int base = blockIdx.x * 128;

    // phase A: aggregate
    for (int i = 0; i < 16; ++i) {
        int vl = wave * 16 + i;
        int v = base + vl;
        float a0 = 0.f, a1 = 0.f;
        if (v < N_NODES) {
            float di = dinv[v];
            float sw = di * di;
            float2 hs = ((const float2*)(T + (size_t)v * 128))[lane];
            a0 = sw * hs.x; a1 = sw * hs.y;
            int beg = offs[v], end = offs[v + 1];
            int j = beg;
            for (; j + 4 <= end; j += 4) {
                int   s0 = csr_src[j],   s1 = csr_src[j+1], s2 = csr_src[j+2], s3 = csr_src[j+3];
                float w0 = csr_w[j],     w1 = csr_w[j+1],   w2 = csr_w[j+2],   w3 = csr_w[j+3];
                float2 h0 = ((const float2*)(T + (size_t)s0 * 128))[lane];
                float2 h1 = ((const float2*)(T + (size_t)s1 * 128))[lane];
                float2 h2 = ((const float2*)(T + (size_t)s2 * 128))[lane];
                float2 h3 = ((const float2*)(T + (size_t)s3 * 128))[lane];
                a0 = fmaf(w0, h0.x, fmaf(w1, h1.x, fmaf(w2, h2.x, fmaf(w3, h3.x, a0))));
                a1 = fmaf(w0, h0.y, fmaf(w1, h1.y, fmaf(w2, h2.y, fmaf(w3, h3.y, a1))));
            }
            for (; j < end; ++j) {
                int s = csr_src[j]; float w = csr_w[j];
                float2 hh = ((const float2*)(T + (size_t)s * 128))[lane];
                a0 = fmaf(w, hh.x, a0);
                a1 = fmaf(w, hh.y, a1);
            }
            a0 = fmaxf(a0 + ba[2 * lane], 0.f);
            a1 = fmaxf(a1 + ba[2 * lane + 1], 0.f);
        }
        ((float2*)(sh + vl * 128))[lane] = make_float2(a0, a1);
    }
    __syncthreads();

    // phase B: GEMM sh @ W
    constexpr int CG = OUTC / 4;      // 32 or 16 float4 col-groups
    constexpr int TR = CG / 4;        // 8 or 4 rows per thread
    int tx = t % CG;
    int ty = t / CG;

    float acc[TR][4];
    #pragma unroll
    for (int r = 0; r < TR; ++r) { acc[r][0]=0.f; acc[r][1]=0.f; acc[r][2]=0.f; acc[r][3]=0.f; }

    #pragma unroll 2
    for (int k = 0; k < 128; k += 4) {
        float4 w0 = ((const float4*)(W + (size_t)(k + 0) * OUTC))[tx];
        float4 w1 = ((const float4*)(W + (size_t)(k + 1) * OUTC))[tx];
        float4 w2 = ((const float4*)(W + (size_t)(k + 2) * OUTC))[tx];
        float4 w3 = ((const float4*)(W + (size_t)(k + 3) * OUTC))[tx];
        #pragma unroll
        for (int r = 0; r < TR; ++r) {
            float4 xv = *(const float4*)(sh + (ty * TR + r) * 128 + k);
            acc[r][0] = fmaf(xv.x, w0.x, fmaf(xv.y, w1.x, fmaf(xv.z, w2.x, fmaf(xv.w, w3.x, acc[r][0]))));
            acc[r][1] = fmaf(xv.x, w0.y, fmaf(xv.y, w1.y, fmaf(xv.z, w2.y, fmaf(xv.w, w3.y, acc[r][1]))));
            acc[r][2] = fmaf(xv.x, w0.z, fmaf(xv.y, w1.z, fmaf(xv.z, w2.z, fmaf(xv.w, w3.z, acc[r][2]))));
            acc[r][3] = fmaf(xv.x, w0.w, fmaf(xv.y, w1.w, fmaf(xv.z, w2.w, fmaf(xv.w, w3.w, acc[r][3]))));
        }
    }

    #pragma unroll
    for (int r = 0; r < TR; ++r) {
        int gr = base + ty * TR + r;
        if (gr < N_NODES)
            ((float4*)(O + (size_t)gr * OUTC))[tx] =
                make_float4(acc[r][0], acc[r][1], acc[r][2], acc[r][3]);
    }
}

// ---------------- K4: out = agg64(T) + b3 + x @ Wres + bres ----------------
// Phase A: agg 64-ch into LDS (32KB). Phase B: residual GEMM from global x + add.

__global__ __launch_bounds__(512, 4)
void k_agg64_res(const float* __restrict__ T, const int* __restrict__ offs,
                 const int* __restrict__ csr_src, const float* __restrict__ csr_w,
                 const float* __restrict__ dinv, const float* __restrict__ b3,
                 const float* __restrict__ x, const float* __restrict__ Wres,
                 const float* __restrict__ bres, float* __restrict__ out) {
    __shared__ float sh[128 * 64];
    int t = threadIdx.x;
    int wave = t >> 6, lane = t & 63;
    int base = blockIdx.x * 128;

    // phase A: aggregate 64-ch, 1 ch per lane
    for (int i = 0; i < 16; ++i) {
        int vl = wave * 16 + i;
        int v = base + vl;
        float a = 0.f;
        if (v < N_NODES) {
            float di = dinv[v];
            float sw = di * di;
            a = sw * T[(size_t)v * 64 + lane];
            int beg = offs[v], end = offs[v + 1];
            int j = beg;
            for (; j + 4 <= end; j += 4) {
                int   s0 = csr_src[j],   s1 = csr_src[j+1], s2 = csr_src[j+2], s3 = csr_src[j+3];
                float w0 = csr_w[j],     w1 = csr_w[j+1],   w2 = csr_w[j+2],   w3 = csr_w[j+3];
                float h0 = T[(size_t)s0 * 64 + lane];
                float h1 = T[(size_t)s1 * 64 + lane];
                float h2 = T[(size_t)s2 * 64 + lane];
                float h3 = T[(size_t)s3 * 64 + lane];
                a = fmaf(w0, h0, fmaf(w1, h1, fmaf(w2, h2, fmaf(w3, h3, a))));
            }
            for (; j < end; ++j)
                a = fmaf(csr_w[j], T[(size_t)csr_src[j] * 64 + lane], a);
            a += b3[lane];
        }
        sh[vl * 64 + lane] = a;
    }
    __syncthreads();

    // phase B: residual GEMM x[128 rows,128] @ Wres[128,64] + sh + bres
    int tx = t & 15;          // 16 float4 col groups = 64 cols
    int ty = t >> 4;          // 32 row groups x 4 rows
    float acc[4][4];
    #pragma unroll
    for (int r = 0; r < 4; ++r) { acc[r][0]=0.f; acc[r][1]=0.f; acc[r][2]=0.f; acc[r][3]=0.f; }

    int rows[4];
    #pragma unroll
    for (int r = 0; r < 4; ++r) {
        int gr = base + ty * 4 + r;
        rows[r] = (gr < N_NODES) ? gr : (N_NODES - 1);  // clamp for safe load
    }

    #pragma unroll 2
    for (int k = 0; k < 128; k += 4) {
        float4 w0 = ((const float4*)(Wres + (size_t)(k + 0) * 64))[tx];
        float4 w1 = ((const float4*)(Wres + (size_t)(k + 1) * 64))[tx];
        float4 w2 = ((const float4*)(Wres + (size_t)(k + 2) * 64))[tx];
        float4 w3 = ((const float4*)(Wres + (size_t)(k + 3) * 64))[tx];
        #pragma unroll
        for (int r = 0; r < 4; ++r) {
            float4 xv = *(const float4*)(x + (size_t)rows[r] * 128 + k);
            acc[r][0] = fmaf(xv.x, w0.x, fmaf(xv.y, w1.x, fmaf(xv.z, w2.x, fmaf(xv.w, w3.x, acc[r][0]))));
            acc[r][1] = fmaf(xv.x, w0.y, fmaf(xv.y, w1.y, fmaf(xv.z, w2.y, fmaf(xv.w, w3.y, acc[r][1]))));
            acc[r][2] = fmaf(xv.x, w0.z, fmaf(xv.y, w1.z, fmaf(xv.z, w2.z, fmaf(xv.w, w3.z, acc[r][2]))));
            acc[r][3] = fmaf(xv.x, w0.w, fmaf(xv.y, w1.w, fmaf(xv.z, w2.w, fmaf(xv.w, w3.w, acc[r][3]))));
        }
    }

    float4 bv = ((const float4*)bres)[tx];
    #pragma unroll
    for (int r = 0; r < 4; ++r) {
        int vl = ty * 4 + r;
        int gr = base + vl;
        if (gr < N_NODES) {
            float4 s = ((const float4*)(sh + vl * 64))[tx];
            ((float4*)(out + (size_t)gr * 64))[tx] =
                make_float4(acc[r][0] + bv.x + s.x, acc[r][1] + bv.y + s.y,
                            acc[r][2] + bv.z + s.z, acc[r][3] + bv.w + s.w);
        }
    }
}

// ---------------- launch ----------------

extern "C" void kernel_launch(void* const* d_in, const int* in_sizes, int n_in,
                              void* d_out, int out_size, void* d_ws, size_t ws_size,
                              hipStream_t stream) {
    const float* x    = (const float*)d_in[0];
    const int*   ei   = (const int*)d_in[1];   // [2, E] flat: row=ei[e], col=ei[E+e]
    const float* W1   = (const float*)d_in[2];
    const float* b1   = (const float*)d_in[3];
    const float* W2   = (const float*)d_in[4];
    const float* b2   = (const float*)d_in[5];
    const float* W3   = (const float*)d_in[6];
    const float* b3   = (const float*)d_in[7];
    const float* Wres = (const float*)d_in[8];
    const float* bres = (const float*)d_in[9];
    float* out = (float*)d_out;

    char* base = (char*)d_ws;
    int*   cnt      = (int*)(base);                        // 200704 B slots
    int*   cursor   = (int*)(base + 200704);
    float* dinv     = (float*)(base + 2 * 200704);
    int*   offsets  = (int*)(base + 3 * 200704);           // N+1 ints
    int*   partials = (int*)(base + 4 * 200704);           // 1024 B
    int*   csr_src  = (int*)(base + 4 * 200704 + 1024);
    float* csr_w    = (float*)(base + 4 * 200704 + 1024 + 2560000);
    float* bufA     = (float*)(base + 4 * 200704 + 1024 + 2 * 2560000);
    float* bufB     = bufA + (size_t)N_NODES * 128;

    const int NB_N = (N_NODES + 255) / 256;   // 196
    const int NB_E = (N_EDGES + 255) / 256;   // 2500
    const int NB_F = (N_NODES + 127) / 128;   // 391

    // graph build
    k_init <<<NB_N, 256, 0, stream>>>(cnt, cursor);
    k_count<<<NB_E, 256, 0, stream>>>(ei, cnt);
    k_scan1<<<NB_N, 256, 0, stream>>>(cnt, offsets, partials, dinv);
    k_scan2<<<1,    256, 0, stream>>>(partials, NB_N);
    k_scan3<<<NB_N, 256, 0, stream>>>(offsets, partials);
    k_fill <<<NB_E, 256, 0, stream>>>(ei, dinv, offsets, cursor, csr_src, csr_w);

    // t1 = x@W1
    k_gemm_x<<<NB_F, 512, 0, stream>>>(x, W1, bufA);
    // t2 = relu(agg(t1)+b1) @ W2
    k_agg_gemm<128><<<NB_F, 512, 0, stream>>>(bufA, offsets, csr_src, csr_w, dinv, b1, W2, bufB);
    // t3 = relu(agg(t2)+b2) @ W3
    k_agg_gemm<64><<<NB_F, 512, 0, stream>>>(bufB, offsets, csr_src, csr_w, dinv, b2, W3, bufA);
    // out = agg64(t3) + b3 + x@Wres + bres
    k_agg64_res<<<NB_F, 512, 0, stream>>>(bufA, offsets, csr_src, csr_w, dinv, b3, x, Wres, bres, out);
}

// Round 8
// 488.996 us; speedup vs baseline: 1.0120x; 1.0120x over previous
//
#include <hip/hip_runtime.h>
#include <hip/hip_fp16.h>

#define N_NODES 50000
#define N_EDGES 640000
// channels: 128 -> 128 -> 128 -> 64, residual 128 -> 64
// Intermediate gather tables (t1,t2,t3 = GEMM outputs) stored fp16; all
// accumulation, agg outputs, residual path, and final output in f32.

// ---------------- graph build ----------------

__global__ void k_init(int* __restrict__ cnt, int* __restrict__ cursor) {
    int i = blockIdx.x * blockDim.x + threadIdx.x;
    if (i < N_NODES) { cnt[i] = 0; cursor[i] = 0; }
}

__global__ void k_count(const int* __restrict__ ei, int* __restrict__ cnt) {
    int e = blockIdx.x * blockDim.x + threadIdx.x;
    if (e < N_EDGES) atomicAdd(&cnt[ei[N_EDGES + e]], 1);
}

// scan over cnt -> offsets (exclusive); also emits dinv = rsqrt(cnt+1)
__global__ void k_scan1(const int* __restrict__ cnt, int* __restrict__ offsets,
                        int* __restrict__ partials, float* __restrict__ dinv) {
    __shared__ int s[256];
    int t = threadIdx.x;
    int i = blockIdx.x * 256 + t;
    int v = (i < N_NODES) ? cnt[i] : 0;
    if (i < N_NODES) dinv[i] = rsqrtf((float)(v + 1));  // +1 self-loop, always > 0
    s[t] = v;
    __syncthreads();
    #pragma unroll
    for (int d = 1; d < 256; d <<= 1) {
        int add = (t >= d) ? s[t - d] : 0;
        __syncthreads();
        s[t] += add;
        __syncthreads();
    }
    if (i < N_NODES) offsets[i + 1] = s[t];   // inclusive within block
    if (t == 255) partials[blockIdx.x] = s[255];
    if (i == 0) offsets[0] = 0;
}

__global__ void k_scan2(int* __restrict__ partials, int nb) {
    __shared__ int s[256];
    int t = threadIdx.x;
    int v = (t < nb) ? partials[t] : 0;
    s[t] = v;
    __syncthreads();
    #pragma unroll
    for (int d = 1; d < 256; d <<= 1) {
        int add = (t >= d) ? s[t - d] : 0;
        __syncthreads();
        s[t] += add;
        __syncthreads();
    }
    if (t < nb) partials[t] = s[t] - v;        // exclusive block bases
}

__global__ void k_scan3(int* __restrict__ offsets, const int* __restrict__ partials) {
    int i = blockIdx.x * 256 + threadIdx.x;
    if (i < N_NODES) offsets[i + 1] += partials[blockIdx.x];
}

__global__ void k_fill(const int* __restrict__ ei, const float* __restrict__ dinv,
                       const int* __restrict__ offsets, int* __restrict__ cursor,
                       int* __restrict__ csr_src, float* __restrict__ csr_w) {
    int e = blockIdx.x * blockDim.x + threadIdx.x;
    if (e < N_EDGES) {
        int r = ei[e];
        int c = ei[N_EDGES + e];
        float w = dinv[r] * dinv[c];
        int p = atomicAdd(&cursor[c], 1);
        int idx = offsets[c] + p;
        csr_src[idx] = r;
        csr_w[idx] = w;
    }
}

// ---------------- f32 register GEMM: O[N,OUTC] = A[N,128] @ W[128,OUTC] (+bias) ----------------
// 256 threads, no LDS. Each thread: 8 rows x 1 float4 col-group.
// W rows from global (64KB, L2-resident broadcast). HALF_OUT stores fp16 table.

template <int OUTC, bool HALF_OUT>
__global__ __launch_bounds__(256, 4)
void k_gemm(const float* __restrict__ A, const float* __restrict__ W,
            const float* __restrict__ bias, void* __restrict__ O) {
    constexpr int CG = OUTC / 4;        // float4 col groups: 32 (OUTC=128) / 16 (OUTC=64)
    constexpr int RG = 256 / CG;        // row groups: 8 / 16
    constexpr int TR = 8;               // rows per thread
    constexpr int BM = RG * TR;         // rows per block: 64 / 128

    int t = threadIdx.x;
    int tx = t % CG;
    int ty = t / CG;
    int base = blockIdx.x * BM;

    float acc[TR][4];
    #pragma unroll
    for (int r = 0; r < TR; ++r) { acc[r][0]=0.f; acc[r][1]=0.f; acc[r][2]=0.f; acc[r][3]=0.f; }

    int rows[TR];
    #pragma unroll
    for (int r = 0; r < TR; ++r) {
        int gr = base + ty * TR + r;
        rows[r] = (gr < N_NODES) ? gr : (N_NODES - 1);   // clamp for safe load
    }

    #pragma unroll 2
    for (int k = 0; k < 128; k += 4) {
        float4 w0 = ((const float4*)(W + (size_t)(k + 0) * OUTC))[tx];
        float4 w1 = ((const float4*)(W + (size_t)(k + 1) * OUTC))[tx];
        float4 w2 = ((const float4*)(W + (size_t)(k + 2) * OUTC))[tx];
        float4 w3 = ((const float4*)(W + (size_t)(k + 3) * OUTC))[tx];
        #pragma unroll
        for (int r = 0; r < TR; ++r) {
            float4 xv = *(const float4*)(A + (size_t)rows[r] * 128 + k);
            acc[r][0] = fmaf(xv.x, w0.x, fmaf(xv.y, w1.x, fmaf(xv.z, w2.x, fmaf(xv.w, w3.x, acc[r][0]))));
            acc[r][1] = fmaf(xv.x, w0.y, fmaf(xv.y, w1.y, fmaf(xv.z, w2.y, fmaf(xv.w, w3.y, acc[r][1]))));
            acc[r][2] = fmaf(xv.x, w0.z, fmaf(xv.y, w1.z, fmaf(xv.z, w2.z, fmaf(xv.w, w3.z, acc[r][2]))));
            acc[r][3] = fmaf(xv.x, w0.w, fmaf(xv.y, w1.w, fmaf(xv.z, w2.w, fmaf(xv.w, w3.w, acc[r][3]))));
        }
    }

    float4 bv = make_float4(0.f, 0.f, 0.f, 0.f);
    if (bias) bv = ((const float4*)bias)[tx];
    #pragma unroll
    for (int r = 0; r < TR; ++r) {
        int gr = base + ty * TR + r;
        if (gr < N_NODES) {
            if constexpr (HALF_OUT) {
                __half* Oh = (__half*)O;
                ushort4 p = make_ushort4(
                    __half_as_ushort(__float2half_rn(acc[r][0] + bv.x)),
                    __half_as_ushort(__float2half_rn(acc[r][1] + bv.y)),
                    __half_as_ushort(__float2half_rn(acc[r][2] + bv.z)),
                    __half_as_ushort(__float2half_rn(acc[r][3] + bv.w)));
                *(ushort4*)(Oh + (size_t)gr * OUTC + tx * 4) = p;   // 8B aligned
            } else {
                float* Of = (float*)O;
                ((float4*)(Of + (size_t)gr * OUTC))[tx] =
                    make_float4(acc[r][0] + bv.x, acc[r][1] + bv.y,
                                acc[r][2] + bv.z, acc[r][3] + bv.w);
            }
        }
    }
}

// ---------------- aggregation (round-0 measured-good config; optional fp16 table input) ----------------
// O[v] = sum_{e: col=v} w_e * T[src_e] + dinv[v]^2 * T[v] + bias (+add) [+relu]
// one wave per node; CH=128 -> 2ch/lane, CH=64 -> 1ch/lane. f32 accumulate + f32 output.

template <int CH, bool RELU, bool HASADD, bool HALF_IN>
__global__ __launch_bounds__(256)
void k_agg(const void* __restrict__ Tv, const int* __restrict__ offs,
           const int* __restrict__ csr_src, const float* __restrict__ csr_w,
           const float* __restrict__ dinv, const float* __restrict__ bias,
           const float* __restrict__ add, float* __restrict__ O) {
    int lane = threadIdx.x & 63;
    int v = blockIdx.x * 4 + (threadIdx.x >> 6);
    if (v >= N_NODES) return;
    int beg = offs[v], end = offs[v + 1];
    float di = dinv[v];
    float sw = di * di;

    if constexpr (CH == 128) {
        auto LD = [&](int s) -> float2 {
            if constexpr (HALF_IN)
                return __half22float2(((const __half2*)((const __half*)Tv + (size_t)s * 128))[lane]);
            else
                return ((const float2*)((const float*)Tv + (size_t)s * 128))[lane];
        };
        float2 hs = LD(v);
        float a0 = sw * hs.x, a1 = sw * hs.y;
        int j = beg;
        for (; j + 4 <= end; j += 4) {
            int   s0 = csr_src[j],   s1 = csr_src[j+1], s2 = csr_src[j+2], s3 = csr_src[j+3];
            float w0 = csr_w[j],     w1 = csr_w[j+1],   w2 = csr_w[j+2],   w3 = csr_w[j+3];
            float2 h0 = LD(s0);
            float2 h1 = LD(s1);
            float2 h2 = LD(s2);
            float2 h3 = LD(s3);
            a0 = fmaf(w0, h0.x, fmaf(w1, h1.x, fmaf(w2, h2.x, fmaf(w3, h3.x, a0))));
            a1 = fmaf(w0, h0.y, fmaf(w1, h1.y, fmaf(w2, h2.y, fmaf(w3, h3.y, a1))));
        }
        for (; j < end; ++j) {
            float w = csr_w[j];
            float2 hh = LD(csr_src[j]);
            a0 = fmaf(w, hh.x, a0);
            a1 = fmaf(w, hh.y, a1);
        }
        a0 += bias[2 * lane];
        a1 += bias[2 * lane + 1];
        if constexpr (HASADD) {
            a0 += add[(size_t)v * 128 + 2 * lane];
            a1 += add[(size_t)v * 128 + 2 * lane + 1];
        }
        if constexpr (RELU) { a0 = fmaxf(a0, 0.f); a1 = fmaxf(a1, 0.f); }
        ((float2*)(O + (size_t)v * 128))[lane] = make_float2(a0, a1);
    } else {
        // CH == 64
        auto LD1 = [&](int s) -> float {
            if constexpr (HALF_IN)
                return __half2float(((const __half*)Tv)[(size_t)s * 64 + lane]);
            else
                return ((const float*)Tv)[(size_t)s * 64 + lane];
        };
        float a = sw * LD1(v);
        int j = beg;
        for (; j + 4 <= end; j += 4) {
            int   s0 = csr_src[j],   s1 = csr_src[j+1], s2 = csr_src[j+2], s3 = csr_src[j+3];
            float w0 = csr_w[j],     w1 = csr_w[j+1],   w2 = csr_w[j+2],   w3 = csr_w[j+3];
            float h0 = LD1(s0);
            float h1 = LD1(s1);
            float h2 = LD1(s2);
            float h3 = LD1(s3);
            a = fmaf(w0, h0, fmaf(w1, h1, fmaf(w2, h2, fmaf(w3, h3, a))));
        }
        for (; j < end; ++j)
            a = fmaf(csr_w[j], LD1(csr_src[j]), a);
        a += bias[lane];
        if constexpr (HASADD) a += add[(size_t)v * 64 + lane];
        if constexpr (RELU) a = fmaxf(a, 0.f);
        O[(size_t)v * 64 + lane] = a;
    }
}

// ---------------- launch ----------------

extern "C" void kernel_launch(void* const* d_in, const int* in_sizes, int n_in,
                              void* d_out, int out_size, void* d_ws, size_t ws_size,
                              hipStream_t stream) {
    const float* x    = (const float*)d_in[0];
    const int*   ei   = (const int*)d_in[1];   // [2, E] flat: row=ei[e], col=ei[E+e]
    const float* W1   = (const float*)d_in[2];
    const float* b1   = (const float*)d_in[3];
    const float* W2   = (const float*)d_in[4];
    const float* b2   = (const float*)d_in[5];
    const float* W3   = (const float*)d_in[6];
    const float* b3   = (const float*)d_in[7];
    const float* Wres = (const float*)d_in[8];
    const float* bres = (const float*)d_in[9];
    float* out = (float*)d_out;

    char* base = (char*)d_ws;
    int*    cnt      = (int*)(base);                        // 200704 B slots
    int*    cursor   = (int*)(base + 200704);
    float*  dinv     = (float*)(base + 2 * 200704);
    int*    offsets  = (int*)(base + 3 * 200704);           // N+1 ints
    int*    partials = (int*)(base + 4 * 200704);           // 1024 B
    int*    csr_src  = (int*)(base + 4 * 200704 + 1024);
    float*  csr_w    = (float*)(base + 4 * 200704 + 1024 + 2560000);
    float*  bufA     = (float*)(base + 4 * 200704 + 1024 + 2 * 2560000);            // f32 [N,128] = 25.6 MB
    float*  bufB     = bufA + (size_t)N_NODES * 128;                                 // f32 [N,64]  = 12.8 MB
    __half* bufH     = (__half*)(bufB + (size_t)N_NODES * 64);                       // f16 [N,128] = 12.8 MB
    // total ~57.1 MB, same footprint as previously-passing rounds

    const int NB_N = (N_NODES + 255) / 256;   // 196
    const int NB_E = (N_EDGES + 255) / 256;   // 2500
    const int NB_G128 = (N_NODES + 63) / 64;  // 782  (k_gemm<128>, BM=64)
    const int NB_G64  = (N_NODES + 127) / 128;// 391  (k_gemm<64>,  BM=128)
    const int NB_A = (N_NODES + 3) / 4;       // 12500

    // graph build
    k_init <<<NB_N, 256, 0, stream>>>(cnt, cursor);
    k_count<<<NB_E, 256, 0, stream>>>(ei, cnt);
    k_scan1<<<NB_N, 256, 0, stream>>>(cnt, offsets, partials, dinv);
    k_scan2<<<1,    256, 0, stream>>>(partials, NB_N);
    k_scan3<<<NB_N, 256, 0, stream>>>(offsets, partials);
    k_fill <<<NB_E, 256, 0, stream>>>(ei, dinv, offsets, cursor, csr_src, csr_w);

    // layer 1: t1 = x@W1 (f16) ; h1 = relu(agg(t1)+b1) (f32)
    k_gemm<128, true><<<NB_G128, 256, 0, stream>>>(x, W1, nullptr, (void*)bufH);
    k_agg<128, true, false, true><<<NB_A, 256, 0, stream>>>((const void*)bufH, offsets, csr_src, csr_w, dinv, b1, nullptr, bufA);
    // layer 2: t2 = h1@W2 (f16) ; h2 = relu(agg(t2)+b2) (f32)
    k_gemm<128, true><<<NB_G128, 256, 0, stream>>>(bufA, W2, nullptr, (void*)bufH);
    k_agg<128, true, false, true><<<NB_A, 256, 0, stream>>>((const void*)bufH, offsets, csr_src, csr_w, dinv, b2, nullptr, bufA);
    // layer 3: t3 = h2@W3 (f16) ; res = x@Wres+bres (f32) ; out = agg64(t3)+b3+res
    k_gemm<64, true><<<NB_G64, 256, 0, stream>>>(bufA, W3, nullptr, (void*)bufH);
    k_gemm<64, false><<<NB_G64, 256, 0, stream>>>(x, Wres, bres, (void*)bufB);
    k_agg<64, false, true, true><<<NB_A, 256, 0, stream>>>((const void*)bufH, offsets, csr_src, csr_w, dinv, b3, bufB, out);
}

// Round 10
// 350.213 us; speedup vs baseline: 1.4131x; 1.3963x over previous
//
#include <hip/hip_runtime.h>
#include <hip/hip_fp16.h>

#define N_NODES 50000
#define N_EDGES 640000
// channels: 128 -> 128 -> 128 -> 64, residual 128 -> 64
// GEMMs on MFMA (fp16 in, f32 acc). Gather tables + h1/h2 in fp16.
// Aggregation accumulate + final output in f32.

typedef _Float16 f16x8 __attribute__((ext_vector_type(8)));
typedef float    f32x4 __attribute__((ext_vector_type(4)));

// ---------------- graph build ----------------

__global__ void k_init(int* __restrict__ cnt, int* __restrict__ cursor) {
    int i = blockIdx.x * blockDim.x + threadIdx.x;
    if (i < N_NODES) { cnt[i] = 0; cursor[i] = 0; }
}

__global__ void k_count(const int* __restrict__ ei, int* __restrict__ cnt) {
    int e = blockIdx.x * blockDim.x + threadIdx.x;
    if (e < N_EDGES) atomicAdd(&cnt[ei[N_EDGES + e]], 1);
}

__global__ void k_scan1(const int* __restrict__ cnt, int* __restrict__ offsets,
                        int* __restrict__ partials, float* __restrict__ dinv) {
    __shared__ int s[256];
    int t = threadIdx.x;
    int i = blockIdx.x * 256 + t;
    int v = (i < N_NODES) ? cnt[i] : 0;
    if (i < N_NODES) dinv[i] = rsqrtf((float)(v + 1));  // +1 self-loop, always > 0
    s[t] = v;
    __syncthreads();
    #pragma unroll
    for (int d = 1; d < 256; d <<= 1) {
        int add = (t >= d) ? s[t - d] : 0;
        __syncthreads();
        s[t] += add;
        __syncthreads();
    }
    if (i < N_NODES) offsets[i + 1] = s[t];
    if (t == 255) partials[blockIdx.x] = s[255];
    if (i == 0) offsets[0] = 0;
}

__global__ void k_scan2(int* __restrict__ partials, int nb) {
    __shared__ int s[256];
    int t = threadIdx.x;
    int v = (t < nb) ? partials[t] : 0;
    s[t] = v;
    __syncthreads();
    #pragma unroll
    for (int d = 1; d < 256; d <<= 1) {
        int add = (t >= d) ? s[t - d] : 0;
        __syncthreads();
        s[t] += add;
        __syncthreads();
    }
    if (t < nb) partials[t] = s[t] - v;
}

__global__ void k_scan3(int* __restrict__ offsets, const int* __restrict__ partials) {
    int i = blockIdx.x * 256 + threadIdx.x;
    if (i < N_NODES) offsets[i + 1] += partials[blockIdx.x];
}

__global__ void k_fill(const int* __restrict__ ei, const float* __restrict__ dinv,
                       const int* __restrict__ offsets, int* __restrict__ cursor,
                       int* __restrict__ csr_src, float* __restrict__ csr_w) {
    int e = blockIdx.x * blockDim.x + threadIdx.x;
    if (e < N_EDGES) {
        int r = ei[e];
        int c = ei[N_EDGES + e];
        float w = dinv[r] * dinv[c];
        int p = atomicAdd(&cursor[c], 1);
        int idx = offsets[c] + p;
        csr_src[idx] = r;
        csr_w[idx] = w;
    }
}

// ---------------- converts ----------------

// x f32 [N,128] -> fp16, float4-vectorized
__global__ void k_cvt_x(const float* __restrict__ x, __half* __restrict__ xh) {
    int i = blockIdx.x * 256 + threadIdx.x;       // over N*128/4
    if (i < N_NODES * 32) {
        float4 v = ((const float4*)x)[i];
        ushort4 p = make_ushort4(__half_as_ushort(__float2half_rn(v.x)),
                                 __half_as_ushort(__float2half_rn(v.y)),
                                 __half_as_ushort(__float2half_rn(v.z)),
                                 __half_as_ushort(__float2half_rn(v.w)));
        ((ushort4*)xh)[i] = p;
    }
}

// W f32 [128,OUTC] -> Wt fp16 [OUTC,128] (transpose)
template <int OUTC>
__global__ void k_cvt_wt(const float* __restrict__ W, __half* __restrict__ Wt) {
    int i = blockIdx.x * 256 + threadIdx.x;       // over 128*OUTC
    if (i < 128 * OUTC) {
        int k = i / OUTC, n = i % OUTC;
        Wt[n * 128 + k] = __float2half_rn(W[i]);
    }
}

// ---------------- MFMA GEMM: O[N,OUTC] = Ah[N,128] @ W[128,OUTC] (+bias) ----------------
// fp16 A (row-major), fp16 Wt (= W transposed, [OUTC,128]), f32 accumulate.
// 256 threads = 4 waves; wave handles 16 rows x OUTC. K=128 = 4 MFMA k-steps.
// Fragment mapping (m89-verified): A: lane l elem i -> A[l&15][(l>>4)*8+i];
// B: lane l elem i -> W[(l>>4)*8+i][l&15] = Wt[l&15][(l>>4)*8+i]; D: reg r -> row (l>>4)*4+r, col l&15.

template <int OUTC, bool F32_OUT>
__global__ __launch_bounds__(256)
void k_gemm_mfma(const __half* __restrict__ Ah, const __half* __restrict__ Wt,
                 const float* __restrict__ bias, void* __restrict__ O) {
    constexpr int NT = OUTC / 16;     // col tiles: 8 (OUTC=128) / 4 (OUTC=64)
    int t = threadIdx.x;
    int wave = t >> 6, lane = t & 63;
    int lo = lane & 15, hi = lane >> 4;
    int row0 = blockIdx.x * 64 + wave * 16;

    int arow = row0 + lo;
    if (arow >= N_NODES) arow = N_NODES - 1;      // clamp for safe load
    const __half* Ap = Ah + (size_t)arow * 128 + hi * 8;
    f16x8 a0 = *(const f16x8*)(Ap);
    f16x8 a1 = *(const f16x8*)(Ap + 32);
    f16x8 a2 = *(const f16x8*)(Ap + 64);
    f16x8 a3 = *(const f16x8*)(Ap + 96);

    f32x4 acc[NT];
    #pragma unroll
    for (int n = 0; n < NT; ++n) acc[n] = (f32x4){0.f, 0.f, 0.f, 0.f};

    #pragma unroll
    for (int n = 0; n < NT; ++n) {
        const __half* Wp = Wt + (size_t)(n * 16 + lo) * 128 + hi * 8;
        f16x8 b0 = *(const f16x8*)(Wp);
        f16x8 b1 = *(const f16x8*)(Wp + 32);
        f16x8 b2 = *(const f16x8*)(Wp + 64);
        f16x8 b3 = *(const f16x8*)(Wp + 96);
        acc[n] = __builtin_amdgcn_mfma_f32_16x16x32_f16(a0, b0, acc[n], 0, 0, 0);
        acc[n] = __builtin_amdgcn_mfma_f32_16x16x32_f16(a1, b1, acc[n], 0, 0, 0);
        acc[n] = __builtin_amdgcn_mfma_f32_16x16x32_f16(a2, b2, acc[n], 0, 0, 0);
        acc[n] = __builtin_amdgcn_mfma_f32_16x16x32_f16(a3, b3, acc[n], 0, 0, 0);
    }

    #pragma unroll
    for (int n = 0; n < NT; ++n) {
        float bb = bias ? bias[n * 16 + lo] : 0.f;
        #pragma unroll
        for (int r = 0; r < 4; ++r) {
            int gr = row0 + hi * 4 + r;
            if (gr < N_NODES) {
                float val = acc[n][r] + bb;
                if constexpr (F32_OUT)
                    ((float*)O)[(size_t)gr * OUTC + n * 16 + lo] = val;
                else
                    ((__half*)O)[(size_t)gr * OUTC + n * 16 + lo] = __float2half_rn(val);
            }
        }
    }
}

// ---------------- aggregation (round-0 measured-good config; fp16 tables) ----------------
// O[v] = sum_{e: col=v} w_e * T[src_e] + dinv[v]^2 * T[v] + bias (+add) [+relu]
// one wave per node; CH=128 -> 2ch/lane, CH=64 -> 1ch/lane. f32 accumulate.

template <int CH, bool RELU, bool HASADD, bool HALF_OUT>
__global__ __launch_bounds__(256)
void k_agg(const __half* __restrict__ T, const int* __restrict__ offs,
           const int* __restrict__ csr_src, const float* __restrict__ csr_w,
           const float* __restrict__ dinv, const float* __restrict__ bias,
           const float* __restrict__ add, void* __restrict__ Ov) {
    int lane = threadIdx.x & 63;
    int v = blockIdx.x * 4 + (threadIdx.x >> 6);
    if (v >= N_NODES) return;
    int beg = offs[v], end = offs[v + 1];
    float di = dinv[v];
    float sw = di * di;

    if constexpr (CH == 128) {
        auto LD = [&](int s) -> float2 {
            return __half22float2(((const __half2*)(T + (size_t)s * 128))[lane]);
        };
        float2 hs = LD(v);
        float a0 = sw * hs.x, a1 = sw * hs.y;
        int j = beg;
        for (; j + 4 <= end; j += 4) {
            int   s0 = csr_src[j],   s1 = csr_src[j+1], s2 = csr_src[j+2], s3 = csr_src[j+3];
            float w0 = csr_w[j],     w1 = csr_w[j+1],   w2 = csr_w[j+2],   w3 = csr_w[j+3];
            float2 h0 = LD(s0);
            float2 h1 = LD(s1);
            float2 h2 = LD(s2);
            float2 h3 = LD(s3);
            a0 = fmaf(w0, h0.x, fmaf(w1, h1.x, fmaf(w2, h2.x, fmaf(w3, h3.x, a0))));
            a1 = fmaf(w0, h0.y, fmaf(w1, h1.y, fmaf(w2, h2.y, fmaf(w3, h3.y, a1))));
        }
        for (; j < end; ++j) {
            float w = csr_w[j];
            float2 hh = LD(csr_src[j]);
            a0 = fmaf(w, hh.x, a0);
            a1 = fmaf(w, hh.y, a1);
        }
        a0 += bias[2 * lane];
        a1 += bias[2 * lane + 1];
        if constexpr (HASADD) {
            a0 += add[(size_t)v * 128 + 2 * lane];
            a1 += add[(size_t)v * 128 + 2 * lane + 1];
        }
        if constexpr (RELU) { a0 = fmaxf(a0, 0.f); a1 = fmaxf(a1, 0.f); }
        if constexpr (HALF_OUT)
            ((__half2*)((__half*)Ov + (size_t)v * 128))[lane] = __float22half2_rn(make_float2(a0, a1));
        else
            ((float2*)((float*)Ov + (size_t)v * 128))[lane] = make_float2(a0, a1);
    } else {
        // CH == 64
        auto LD1 = [&](int s) -> float { return __half2float(T[(size_t)s * 64 + lane]); };
        float a = sw * LD1(v);
        int j = beg;
        for (; j + 4 <= end; j += 4) {
            int   s0 = csr_src[j],   s1 = csr_src[j+1], s2 = csr_src[j+2], s3 = csr_src[j+3];
            float w0 = csr_w[j],     w1 = csr_w[j+1],   w2 = csr_w[j+2],   w3 = csr_w[j+3];
            float h0 = LD1(s0);
            float h1 = LD1(s1);
            float h2 = LD1(s2);
            float h3 = LD1(s3);
            a = fmaf(w0, h0, fmaf(w1, h1, fmaf(w2, h2, fmaf(w3, h3, a))));
        }
        for (; j < end; ++j)
            a = fmaf(csr_w[j], LD1(csr_src[j]), a);
        a += bias[lane];
        if constexpr (HASADD) a += add[(size_t)v * 64 + lane];
        if constexpr (RELU) a = fmaxf(a, 0.f);
        ((float*)Ov)[(size_t)v * 64 + lane] = a;
    }
}

// ---------------- launch ----------------

extern "C" void kernel_launch(void* const* d_in, const int* in_sizes, int n_in,
                              void* d_out, int out_size, void* d_ws, size_t ws_size,
                              hipStream_t stream) {
    const float* x    = (const float*)d_in[0];
    const int*   ei   = (const int*)d_in[1];   // [2, E] flat: row=ei[e], col=ei[E+e]
    const float* W1   = (const float*)d_in[2];
    const float* b1   = (const float*)d_in[3];
    const float* W2   = (const float*)d_in[4];
    const float* b2   = (const float*)d_in[5];
    const float* W3   = (const float*)d_in[6];
    const float* b3   = (const float*)d_in[7];
    const float* Wres = (const float*)d_in[8];
    const float* bres = (const float*)d_in[9];
    float* out = (float*)d_out;

    char* p = (char*)d_ws;
    int*    cnt      = (int*)p;      p += 200704;
    int*    cursor   = (int*)p;      p += 200704;
    float*  dinv     = (float*)p;    p += 200704;
    int*    offsets  = (int*)p;      p += 200704;           // N+1 ints fits
    int*    partials = (int*)p;      p += 1024;
    int*    csr_src  = (int*)p;      p += (size_t)N_EDGES * 4;
    float*  csr_w    = (float*)p;    p += (size_t)N_EDGES * 4;
    __half* xh       = (__half*)p;   p += (size_t)N_NODES * 128 * 2;   // x fp16
    __half* tabH     = (__half*)p;   p += (size_t)N_NODES * 128 * 2;   // t1/t2/t3 tables
    __half* hH       = (__half*)p;   p += (size_t)N_NODES * 128 * 2;   // h1/h2
    float*  resB     = (float*)p;    p += (size_t)N_NODES * 64 * 4;    // residual f32
    __half* Wt1      = (__half*)p;   p += 128 * 128 * 2;
    __half* Wt2      = (__half*)p;   p += 128 * 128 * 2;
    __half* Wt3      = (__half*)p;   p += 128 * 64 * 2;
    __half* WtR      = (__half*)p;   p += 128 * 64 * 2;
    // total ~58 MB (ws is ~256 MB per harness poison fill)

    const int NB_N = (N_NODES + 255) / 256;   // 196
    const int NB_E = (N_EDGES + 255) / 256;   // 2500
    const int NB_M = (N_NODES + 63) / 64;     // 782  (MFMA gemm, 64 rows/block)
    const int NB_A = (N_NODES + 3) / 4;       // 12500
    const int NB_CX = (N_NODES * 32 + 255) / 256;  // 6250 (x convert, float4 units)

    // graph build
    k_init <<<NB_N, 256, 0, stream>>>(cnt, cursor);
    k_count<<<NB_E, 256, 0, stream>>>(ei, cnt);
    k_scan1<<<NB_N, 256, 0, stream>>>(cnt, offsets, partials, dinv);
    k_scan2<<<1,    256, 0, stream>>>(partials, NB_N);
    k_scan3<<<NB_N, 256, 0, stream>>>(offsets, partials);
    k_fill <<<NB_E, 256, 0, stream>>>(ei, dinv, offsets, cursor, csr_src, csr_w);

    // converts
    k_cvt_x<<<NB_CX, 256, 0, stream>>>(x, xh);
    k_cvt_wt<128><<<64, 256, 0, stream>>>(W1, Wt1);
    k_cvt_wt<128><<<64, 256, 0, stream>>>(W2, Wt2);
    k_cvt_wt<64> <<<32, 256, 0, stream>>>(W3, Wt3);
    k_cvt_wt<64> <<<32, 256, 0, stream>>>(Wres, WtR);

    // layer 1: t1 = x@W1 (fp16) ; h1 = relu(agg(t1)+b1) (fp16)
    k_gemm_mfma<128, false><<<NB_M, 256, 0, stream>>>(xh, Wt1, nullptr, (void*)tabH);
    k_agg<128, true, false, true><<<NB_A, 256, 0, stream>>>(tabH, offsets, csr_src, csr_w, dinv, b1, nullptr, (void*)hH);
    // layer 2: t2 = h1@W2 ; h2 = relu(agg(t2)+b2)
    k_gemm_mfma<128, false><<<NB_M, 256, 0, stream>>>(hH, Wt2, nullptr, (void*)tabH);
    k_agg<128, true, false, true><<<NB_A, 256, 0, stream>>>(tabH, offsets, csr_src, csr_w, dinv, b2, nullptr, (void*)hH);
    // layer 3: t3 = h2@W3 (fp16) ; res = x@Wres+bres (f32) ; out = agg64(t3)+b3+res
    k_gemm_mfma<64, false><<<NB_M, 256, 0, stream>>>(hH, Wt3, nullptr, (void*)tabH);
    k_gemm_mfma<64, true> <<<NB_M, 256, 0, stream>>>(xh, WtR, bres, (void*)resB);
    k_agg<64, false, true, false><<<NB_A, 256, 0, stream>>>(tabH, offsets, csr_src, csr_w, dinv, b3, resB, (void*)out);
}